// Round 12
// baseline (121.461 us; speedup 1.0000x reference)
//
#include <hip/hip_runtime.h>

typedef _Float16 half8 __attribute__((ext_vector_type(8)));
typedef float f32x4 __attribute__((ext_vector_type(4)));
typedef unsigned short u16x8 __attribute__((ext_vector_type(8)));

#define LOG2E 1.44269504088896340736f

constexpr int NB = 16, LQ = 1024, LK = 1024, DX = 512, DVD = 512;
constexpr int QBLK = 64, KVB = 64, NCH = LK / KVB;   // 16 chunks of 64 kv
constexpr int TILE = KVB * DX;                        // 32768 u16 = 64 KB

static __device__ __forceinline__ unsigned short f2h(float f) {
  union { _Float16 h; unsigned short u; } c; c.h = (_Float16)f; return c.u;
}
static __device__ __forceinline__ unsigned int pack2(float a, float b) {
  union { _Float16 h[2]; unsigned int u; } c;
  c.h[0] = (_Float16)a; c.h[1] = (_Float16)b; return c.u;
}
static __device__ __forceinline__ void gload16(const unsigned short* g, unsigned short* l) {
  __builtin_amdgcn_global_load_lds(
      (const __attribute__((address_space(1))) unsigned int*)g,
      (__attribute__((address_space(3))) unsigned int*)l, 16, 0, 0);
}

// ---- prep (r7-verified, KVB=64): f32 -> f16 layout bake into 64-KB tiles.
// K -> Kw[b][c][part=x/8 (64)][kv (64)][8]
// V -> Vw[b][c][pv=kv/8 (8)][d (512)][8]
__global__ __launch_bounds__(256) void prep_kv(
    const float* __restrict__ K, const float* __restrict__ V,
    unsigned short* __restrict__ Kw, unsigned short* __restrict__ Vw) {
  __shared__ float tile[32][520];
  const int bidx = blockIdx.x;
  const bool isV = bidx >= NB * NCH * 2;
  const int r = isV ? bidx - NB * NCH * 2 : bidx;   // b*32 + c*2 + half
  const int b = r >> 5, sub = r & 31, c = sub >> 1, half = sub & 1;
  const int t = (int)threadIdx.x;

  const float* src = (isV ? V : K) + ((size_t)b * LK + c * 64 + half * 32) * DX;
#pragma unroll
  for (int i = 0; i < 16; ++i) {
    int idx = t + i * 256;
    int rr = idx >> 7, cc = (idx & 127) * 4;
    float4 v = *(const float4*)(src + (size_t)idx * 4);
    *(float4*)&tile[rr][cc] = v;
  }
  __syncthreads();

  unsigned short* dst = (isV ? Vw : Kw) + (size_t)(b * NCH + c) * TILE;
  if (!isV) {
#pragma unroll
    for (int k = 0; k < 8; ++k) {
      int obi = t * 8 + k;
      int p = obi >> 5, kvloc = obi & 31;
      const float* rp = &tile[kvloc][p * 8];
      u16x8 o = { f2h(rp[0]), f2h(rp[1]), f2h(rp[2]), f2h(rp[3]),
                  f2h(rp[4]), f2h(rp[5]), f2h(rp[6]), f2h(rp[7]) };
      *(u16x8*)(dst + p * 512 + (half * 32 + kvloc) * 8) = o;
    }
  } else {
#pragma unroll
    for (int k = 0; k < 8; ++k) {
      int vbi = t * 8 + k;
      int pvloc = vbi >> 9, d = vbi & 511;
      u16x8 o = { f2h(tile[pvloc * 8 + 0][d]), f2h(tile[pvloc * 8 + 1][d]),
                  f2h(tile[pvloc * 8 + 2][d]), f2h(tile[pvloc * 8 + 3][d]),
                  f2h(tile[pvloc * 8 + 4][d]), f2h(tile[pvloc * 8 + 5][d]),
                  f2h(tile[pvloc * 8 + 6][d]), f2h(tile[pvloc * 8 + 7][d]) };
      *(u16x8*)(dst + (half * 4 + pvloc) * 4096 + d * 8) = o;
    }
  }
}

// ---- main: wave-specialized, KVB=64, V direct-from-L2, 1 barrier/phase.
// 12 waves: 0..3 QK (16q x 64kv, in-wave softmax); 4..11 PV (64q x 64d) + K DMA.
__global__ __launch_bounds__(768, 3) void attn_ws2(
    const float* __restrict__ Qf, const unsigned short* __restrict__ Kw,
    const unsigned short* __restrict__ Vw, float* __restrict__ Out) {
  __shared__ __align__(16) unsigned short Kl[2][TILE];       // 128 KB
  __shared__ __align__(16) unsigned short Pl[2][8 * 64 * 8]; // 16 KB
  __shared__ __align__(16) float sml[2][64];
  __shared__ __align__(16) float lfin[64];
  __shared__ __align__(16) int rflag[2][4];

  const int bid = blockIdx.x;
  const int logical = (bid & 7) * 32 + (bid >> 3);  // XCD-chunked: 2 batches/XCD
  const int b  = logical >> 4;
  const int qt = logical & 15;
  const int tid = (int)threadIdx.x;
  const int lane = tid & 63;
  const int wave = tid >> 6;            // 0..11
  const bool isQK = wave < 4;
  const int qs = wave;                  // QK q-sub (16 q)
  const int wd = wave - 4;              // PV d-slice (64 d)
  const int c15 = lane & 15;
  const int g4  = lane >> 4;
  const int rbase = g4 * 4;
  const int d0 = wd * 64;

  // ---- QK: Q fragments (16 ks), pre-scaled by LOG2E. PV: acc[16].
  half8 qfrag[16];
  f32x4 acc[16];
  float mr = -3.0e38f, lr = 0.f;
  if (isQK) {
    const float* qrow = Qf + ((size_t)b * LQ + qt * QBLK + qs * 16 + c15) * DX + g4 * 8;
#pragma unroll
    for (int ks = 0; ks < 16; ++ks) {
      float4 a0 = *(const float4*)(qrow + ks * 32);
      float4 a1 = *(const float4*)(qrow + ks * 32 + 4);
      half8 f;
      f[0] = (_Float16)(a0.x * LOG2E); f[1] = (_Float16)(a0.y * LOG2E);
      f[2] = (_Float16)(a0.z * LOG2E); f[3] = (_Float16)(a0.w * LOG2E);
      f[4] = (_Float16)(a1.x * LOG2E); f[5] = (_Float16)(a1.y * LOG2E);
      f[6] = (_Float16)(a1.z * LOG2E); f[7] = (_Float16)(a1.w * LOG2E);
      qfrag[ks] = f;
    }
  } else {
#pragma unroll
    for (int i = 0; i < 16; ++i) acc[i] = (f32x4){0.f, 0.f, 0.f, 0.f};
  }

  // K staging owned by PV threads (tid >= 256 -> 512 threads, 8 insts each)
  const int st = tid - 256;
  const unsigned short* kg = Kw + (size_t)b * NCH * TILE + st * 8;
  const unsigned short* vgb = Vw + (size_t)b * NCH * TILE;

  if (tid >= 256) {
#pragma unroll
    for (int ii = 0; ii < 8; ++ii) gload16(kg + ii * 4096, &Kl[0][st * 8 + ii * 4096]);
  }
  __syncthreads();

  for (int ph = 0; ph <= NCH; ++ph) {
    const int cb = ph & 1, pb = cb ^ 1;

    if (isQK) {
      if (ph < NCH) {
        // ---- QK^T chunk ph: 4 kv-tiles x 16 ks, 4 independent chains
        f32x4 cs0 = {0.f,0.f,0.f,0.f}, cs1 = {0.f,0.f,0.f,0.f};
        f32x4 cs2 = {0.f,0.f,0.f,0.f}, cs3 = {0.f,0.f,0.f,0.f};
        {
          const unsigned short* kb = &Kl[cb][c15 * 8];
          __builtin_amdgcn_s_setprio(1);
#pragma unroll
          for (int ks = 0; ks < 16; ++ks) {
            const int po = (ks * 4 + g4) * 512;          // part = ks*4+g4
            half8 a0 = *(const half8*)(kb + po);         // kv = c15
            half8 a1 = *(const half8*)(kb + po + 128);   // kv = 16+c15
            half8 a2 = *(const half8*)(kb + po + 256);   // kv = 32+c15
            half8 a3 = *(const half8*)(kb + po + 384);   // kv = 48+c15
            cs0 = __builtin_amdgcn_mfma_f32_16x16x32_f16(a0, qfrag[ks], cs0, 0, 0, 0);
            cs1 = __builtin_amdgcn_mfma_f32_16x16x32_f16(a1, qfrag[ks], cs1, 0, 0, 0);
            cs2 = __builtin_amdgcn_mfma_f32_16x16x32_f16(a2, qfrag[ks], cs2, 0, 0, 0);
            cs3 = __builtin_amdgcn_mfma_f32_16x16x32_f16(a3, qfrag[ks], cs3, 0, 0, 0);
          }
          __builtin_amdgcn_s_setprio(0);
        }

        // ---- in-wave online softmax (q = c15), defer-max THR=8
        float pm = fmaxf(fmaxf(fmaxf(cs0[0], cs0[1]), fmaxf(cs0[2], cs0[3])),
                         fmaxf(fmaxf(cs1[0], cs1[1]), fmaxf(cs1[2], cs1[3])));
        pm = fmaxf(pm, fmaxf(fmaxf(fmaxf(cs2[0], cs2[1]), fmaxf(cs2[2], cs2[3])),
                             fmaxf(fmaxf(cs3[0], cs3[1]), fmaxf(cs3[2], cs3[3]))));
        pm = fmaxf(pm, __shfl_xor(pm, 16, 64));
        pm = fmaxf(pm, __shfl_xor(pm, 32, 64));
        const bool resc = __any(pm > mr + 8.0f);
        float scl = 1.0f;
        if (resc) {
          float mn = fmaxf(mr, pm);
          scl = exp2f(mr - mn);
          mr = mn;
        }
        if (g4 == 0) sml[cb][qs * 16 + c15] = scl;
        if (lane == 0) rflag[cb][qs] = resc ? 1 : 0;

        float p0[4], p1[4], p2[4], p3[4];
#pragma unroll
        for (int j = 0; j < 4; ++j) {
          p0[j] = exp2f(cs0[j] - mr);
          p1[j] = exp2f(cs1[j] - mr);
          p2[j] = exp2f(cs2[j] - mr);
          p3[j] = exp2f(cs3[j] - mr);
        }
        // ---- P write: q=qs*16+c15, kv = kvt*16 + g4*4 + j
        {
          unsigned short* pw = &Pl[cb][(g4 >> 1) * 512 + (qs * 16 + c15) * 8 + (g4 & 1) * 4];
          uint2 w0 = { pack2(p0[0], p0[1]), pack2(p0[2], p0[3]) };
          uint2 w1 = { pack2(p1[0], p1[1]), pack2(p1[2], p1[3]) };
          uint2 w2 = { pack2(p2[0], p2[1]), pack2(p2[2], p2[3]) };
          uint2 w3 = { pack2(p3[0], p3[1]), pack2(p3[2], p3[3]) };
          *(uint2*)pw          = w0;   // pp = 0 + (g4>>1)
          *(uint2*)(pw + 1024) = w1;   // pp = 2 + (g4>>1)
          *(uint2*)(pw + 2048) = w2;   // pp = 4 + (g4>>1)
          *(uint2*)(pw + 3072) = w3;   // pp = 6 + (g4>>1)
        }
        float ps = ((p0[0] + p0[1]) + (p0[2] + p0[3])) + ((p1[0] + p1[1]) + (p1[2] + p1[3]))
                 + ((p2[0] + p2[1]) + (p2[2] + p2[3])) + ((p3[0] + p3[1]) + (p3[2] + p3[3]));
        ps += __shfl_xor(ps, 16, 64);
        ps += __shfl_xor(ps, 32, 64);
        lr = lr * scl + ps;
        if (ph == NCH - 1 && g4 == 0) lfin[qs * 16 + c15] = lr;
      }
    } else {
      // ---- PV chunk ph-1 (issue bv global loads FIRST: older than K DMA)
      half8 bv[2][4];
      if (ph > 0) {
        const unsigned short* vt = vgb + (size_t)(ph - 1) * TILE;
#pragma unroll
        for (int t = 0; t < 2; ++t)
#pragma unroll
          for (int n = 0; n < 4; ++n)
            bv[t][n] = *(const half8*)(vt + (t * 4 + g4) * 4096 + (d0 + n * 16 + c15) * 8);
      }
      // ---- issue K(ph+1) DMA into Kl[pb]
      if (ph + 1 < NCH) {
        const unsigned short* ks_ = kg + (size_t)(ph + 1) * TILE;
#pragma unroll
        for (int ii = 0; ii < 8; ++ii)
          gload16(ks_ + ii * 4096, &Kl[pb][st * 8 + ii * 4096]);
      }
      if (ph > 0) {
        half8 pa[4][2];
#pragma unroll
        for (int s = 0; s < 4; ++s)
#pragma unroll
          for (int t = 0; t < 2; ++t)
            pa[s][t] = *(const half8*)&Pl[pb][(t * 4 + g4) * 512 + (s * 16 + c15) * 8];
        int4 f4 = *(const int4*)&rflag[pb][0];
        const int fl = f4.x | f4.y | f4.z | f4.w;
        if (fl) {
#pragma unroll
          for (int s = 0; s < 4; ++s) {
            f32x4 sv = *(const f32x4*)&sml[pb][s * 16 + rbase];
#pragma unroll
            for (int n = 0; n < 4; ++n)
#pragma unroll
              for (int j = 0; j < 4; ++j) acc[s * 4 + n][j] *= sv[j];
          }
        }
        __builtin_amdgcn_s_setprio(1);
#pragma unroll
        for (int s = 0; s < 4; ++s)
#pragma unroll
          for (int n = 0; n < 4; ++n) {
            acc[s * 4 + n] = __builtin_amdgcn_mfma_f32_16x16x32_f16(pa[s][0], bv[0][n], acc[s * 4 + n], 0, 0, 0);
            acc[s * 4 + n] = __builtin_amdgcn_mfma_f32_16x16x32_f16(pa[s][1], bv[1][n], acc[s * 4 + n], 0, 0, 0);
          }
        __builtin_amdgcn_s_setprio(0);
      }
    }

    // ---- single per-phase barrier: PV threads drain K DMA (+own loads);
    //      QK threads have no vmem outstanding (vmcnt free for them).
    asm volatile("s_waitcnt vmcnt(0) lgkmcnt(0)" ::: "memory");
    __builtin_amdgcn_s_barrier();
    __builtin_amdgcn_sched_barrier(0);
  }

  // ---- epilogue (PV waves hold O): O /= l, store f32
  if (!isQK) {
#pragma unroll
    for (int s = 0; s < 4; ++s) {
      f32x4 lv = *(const f32x4*)&lfin[s * 16 + rbase];
      float inv[4];
#pragma unroll
      for (int j = 0; j < 4; ++j) inv[j] = 1.0f / lv[j];
      float* ob = Out + ((size_t)b * LQ + qt * QBLK + s * 16 + rbase) * DVD + d0 + c15;
#pragma unroll
      for (int n = 0; n < 4; ++n)
#pragma unroll
        for (int j = 0; j < 4; ++j)
          ob[(size_t)j * DVD + n * 16] = acc[s * 4 + n][j] * inv[j];
    }
  }
}

extern "C" void kernel_launch(void* const* d_in, const int* in_sizes, int n_in,
                              void* d_out, int out_size, void* d_ws, size_t ws_size,
                              hipStream_t stream) {
  const float* Qf = (const float*)d_in[0];
  const float* Kf = (const float*)d_in[1];
  const float* Vf = (const float*)d_in[2];
  float* Out = (float*)d_out;

  unsigned short* Kw = (unsigned short*)d_ws;
  unsigned short* Vw = Kw + (size_t)NB * NCH * TILE;   // 16.7 MB each

  prep_kv<<<NB * NCH * 2 * 2, 256, 0, stream>>>(Kf, Vf, Kw, Vw);
  attn_ws2<<<NB * (LQ / QBLK), 768, 0, stream>>>(Qf, Kw, Vw, Out);
}

// Round 13
// 105.724 us; speedup vs baseline: 1.1488x; 1.1488x over previous
//
#include <hip/hip_runtime.h>

typedef _Float16 half8 __attribute__((ext_vector_type(8)));
typedef float f32x4 __attribute__((ext_vector_type(4)));
typedef unsigned short u16x8 __attribute__((ext_vector_type(8)));

#define LOG2E 1.44269504088896340736f

constexpr int NB = 16, LQ = 1024, LK = 1024, DX = 512, DVD = 512;
constexpr int QBLK = 64, KVB = 64, NCH = LK / KVB;   // 16 chunks of 64 kv
constexpr int TILE = KVB * DX;                        // 32768 u16 = 64 KB

static __device__ __forceinline__ unsigned short f2h(float f) {
  union { _Float16 h; unsigned short u; } c; c.h = (_Float16)f; return c.u;
}
static __device__ __forceinline__ unsigned int pack2(float a, float b) {
  union { _Float16 h[2]; unsigned int u; } c;
  c.h[0] = (_Float16)a; c.h[1] = (_Float16)b; return c.u;
}
static __device__ __forceinline__ void gload16(const unsigned short* g, unsigned short* l) {
  __builtin_amdgcn_global_load_lds(
      (const __attribute__((address_space(1))) unsigned int*)g,
      (__attribute__((address_space(3))) unsigned int*)l, 16, 0, 0);
}

// ---- prep (r7-verified, KVB=64): f32 -> f16 layout bake into 64-KB tiles.
// K -> Kw[b][c][part=x/8 (64)][kv (64)][8]
// V -> Vw[b][c][pv=kv/8 (8)][d (512)][8]
__global__ __launch_bounds__(256) void prep_kv(
    const float* __restrict__ K, const float* __restrict__ V,
    unsigned short* __restrict__ Kw, unsigned short* __restrict__ Vw) {
  __shared__ float tile[32][520];
  const int bidx = blockIdx.x;
  const bool isV = bidx >= NB * NCH * 2;
  const int r = isV ? bidx - NB * NCH * 2 : bidx;   // b*32 + c*2 + half
  const int b = r >> 5, sub = r & 31, c = sub >> 1, half = sub & 1;
  const int t = (int)threadIdx.x;

  const float* src = (isV ? V : K) + ((size_t)b * LK + c * 64 + half * 32) * DX;
#pragma unroll
  for (int i = 0; i < 16; ++i) {
    int idx = t + i * 256;
    int rr = idx >> 7, cc = (idx & 127) * 4;
    float4 v = *(const float4*)(src + (size_t)idx * 4);
    *(float4*)&tile[rr][cc] = v;
  }
  __syncthreads();

  unsigned short* dst = (isV ? Vw : Kw) + (size_t)(b * NCH + c) * TILE;
  if (!isV) {
#pragma unroll
    for (int k = 0; k < 8; ++k) {
      int obi = t * 8 + k;
      int p = obi >> 5, kvloc = obi & 31;
      const float* rp = &tile[kvloc][p * 8];
      u16x8 o = { f2h(rp[0]), f2h(rp[1]), f2h(rp[2]), f2h(rp[3]),
                  f2h(rp[4]), f2h(rp[5]), f2h(rp[6]), f2h(rp[7]) };
      *(u16x8*)(dst + p * 512 + (half * 32 + kvloc) * 8) = o;
    }
  } else {
#pragma unroll
    for (int k = 0; k < 8; ++k) {
      int vbi = t * 8 + k;
      int pvloc = vbi >> 9, d = vbi & 511;
      u16x8 o = { f2h(tile[pvloc * 8 + 0][d]), f2h(tile[pvloc * 8 + 1][d]),
                  f2h(tile[pvloc * 8 + 2][d]), f2h(tile[pvloc * 8 + 3][d]),
                  f2h(tile[pvloc * 8 + 4][d]), f2h(tile[pvloc * 8 + 5][d]),
                  f2h(tile[pvloc * 8 + 6][d]), f2h(tile[pvloc * 8 + 7][d]) };
      *(u16x8*)(dst + (half * 4 + pvloc) * 4096 + d * 8) = o;
    }
  }
}

// ---- main: wave-specialized, KVB=64, V direct-from-L2, 1 barrier/phase.
// 12 waves: 0..3 QK (16q x 64kv, in-wave softmax); 4..11 PV (64q x 64d) + K DMA.
// NOTE: plain __launch_bounds__(768) -- the (768,3) variant capped VGPR at 84
// and spilled ~60 MB/dispatch to scratch (r12 post-mortem).
__global__ __launch_bounds__(768) void attn_ws3(
    const float* __restrict__ Qf, const unsigned short* __restrict__ Kw,
    const unsigned short* __restrict__ Vw, float* __restrict__ Out) {
  __shared__ __align__(16) unsigned short Kl[2][TILE];       // 128 KB
  __shared__ __align__(16) unsigned short Pl[2][8 * 64 * 8]; // 16 KB
  __shared__ __align__(16) float sml[2][64];
  __shared__ __align__(16) float lfin[64];
  __shared__ __align__(16) int rflag[2][4];

  const int bid = blockIdx.x;
  const int logical = (bid & 7) * 32 + (bid >> 3);  // XCD-chunked: 2 batches/XCD
  const int b  = logical >> 4;
  const int qt = logical & 15;
  const int tid = (int)threadIdx.x;
  const int lane = tid & 63;
  const int wave = tid >> 6;            // 0..11
  const bool isQK = wave < 4;
  const int qs = wave;                  // QK q-sub (16 q)
  const int wd = wave - 4;              // PV d-slice (64 d)
  const int c15 = lane & 15;
  const int g4  = lane >> 4;
  const int rbase = g4 * 4;
  const int d0 = wd * 64;

  // ---- QK: Q fragments (16 ks), pre-scaled by LOG2E. PV: acc[16].
  half8 qfrag[16];
  f32x4 acc[16];
  float mr = -3.0e38f, lr = 0.f;
  if (isQK) {
    const float* qrow = Qf + ((size_t)b * LQ + qt * QBLK + qs * 16 + c15) * DX + g4 * 8;
#pragma unroll
    for (int ks = 0; ks < 16; ++ks) {
      float4 a0 = *(const float4*)(qrow + ks * 32);
      float4 a1 = *(const float4*)(qrow + ks * 32 + 4);
      half8 f;
      f[0] = (_Float16)(a0.x * LOG2E); f[1] = (_Float16)(a0.y * LOG2E);
      f[2] = (_Float16)(a0.z * LOG2E); f[3] = (_Float16)(a0.w * LOG2E);
      f[4] = (_Float16)(a1.x * LOG2E); f[5] = (_Float16)(a1.y * LOG2E);
      f[6] = (_Float16)(a1.z * LOG2E); f[7] = (_Float16)(a1.w * LOG2E);
      qfrag[ks] = f;
    }
  } else {
#pragma unroll
    for (int i = 0; i < 16; ++i) acc[i] = (f32x4){0.f, 0.f, 0.f, 0.f};
  }

  // K staging owned by PV threads (tid >= 256 -> 512 threads, 8 insts each)
  const int st = tid - 256;
  const unsigned short* kg = Kw + (size_t)b * NCH * TILE + st * 8;
  const unsigned short* vgb = Vw + (size_t)b * NCH * TILE;

  if (tid >= 256) {
#pragma unroll
    for (int ii = 0; ii < 8; ++ii) gload16(kg + ii * 4096, &Kl[0][st * 8 + ii * 4096]);
  }
  __syncthreads();

  for (int ph = 0; ph <= NCH; ++ph) {
    const int cb = ph & 1, pb = cb ^ 1;

    if (isQK) {
      if (ph < NCH) {
        // ---- QK^T chunk ph: 4 kv-tiles x 16 ks, 4 independent chains
        f32x4 cs0 = {0.f,0.f,0.f,0.f}, cs1 = {0.f,0.f,0.f,0.f};
        f32x4 cs2 = {0.f,0.f,0.f,0.f}, cs3 = {0.f,0.f,0.f,0.f};
        {
          const unsigned short* kb = &Kl[cb][c15 * 8];
          __builtin_amdgcn_s_setprio(1);
#pragma unroll
          for (int ks = 0; ks < 16; ++ks) {
            const int po = (ks * 4 + g4) * 512;          // part = ks*4+g4
            half8 a0 = *(const half8*)(kb + po);         // kv = c15
            half8 a1 = *(const half8*)(kb + po + 128);   // kv = 16+c15
            half8 a2 = *(const half8*)(kb + po + 256);   // kv = 32+c15
            half8 a3 = *(const half8*)(kb + po + 384);   // kv = 48+c15
            cs0 = __builtin_amdgcn_mfma_f32_16x16x32_f16(a0, qfrag[ks], cs0, 0, 0, 0);
            cs1 = __builtin_amdgcn_mfma_f32_16x16x32_f16(a1, qfrag[ks], cs1, 0, 0, 0);
            cs2 = __builtin_amdgcn_mfma_f32_16x16x32_f16(a2, qfrag[ks], cs2, 0, 0, 0);
            cs3 = __builtin_amdgcn_mfma_f32_16x16x32_f16(a3, qfrag[ks], cs3, 0, 0, 0);
          }
          __builtin_amdgcn_s_setprio(0);
        }

        // ---- in-wave online softmax (q = c15), defer-max THR=8
        float pm = fmaxf(fmaxf(fmaxf(cs0[0], cs0[1]), fmaxf(cs0[2], cs0[3])),
                         fmaxf(fmaxf(cs1[0], cs1[1]), fmaxf(cs1[2], cs1[3])));
        pm = fmaxf(pm, fmaxf(fmaxf(fmaxf(cs2[0], cs2[1]), fmaxf(cs2[2], cs2[3])),
                             fmaxf(fmaxf(cs3[0], cs3[1]), fmaxf(cs3[2], cs3[3]))));
        pm = fmaxf(pm, __shfl_xor(pm, 16, 64));
        pm = fmaxf(pm, __shfl_xor(pm, 32, 64));
        const bool resc = __any(pm > mr + 8.0f);
        float scl = 1.0f;
        if (resc) {
          float mn = fmaxf(mr, pm);
          scl = exp2f(mr - mn);
          mr = mn;
        }
        if (g4 == 0) sml[cb][qs * 16 + c15] = scl;
        if (lane == 0) rflag[cb][qs] = resc ? 1 : 0;

        float p0[4], p1[4], p2[4], p3[4];
#pragma unroll
        for (int j = 0; j < 4; ++j) {
          p0[j] = exp2f(cs0[j] - mr);
          p1[j] = exp2f(cs1[j] - mr);
          p2[j] = exp2f(cs2[j] - mr);
          p3[j] = exp2f(cs3[j] - mr);
        }
        // ---- P write: q=qs*16+c15, kv = kvt*16 + g4*4 + j
        {
          unsigned short* pw = &Pl[cb][(g4 >> 1) * 512 + (qs * 16 + c15) * 8 + (g4 & 1) * 4];
          uint2 w0 = { pack2(p0[0], p0[1]), pack2(p0[2], p0[3]) };
          uint2 w1 = { pack2(p1[0], p1[1]), pack2(p1[2], p1[3]) };
          uint2 w2 = { pack2(p2[0], p2[1]), pack2(p2[2], p2[3]) };
          uint2 w3 = { pack2(p3[0], p3[1]), pack2(p3[2], p3[3]) };
          *(uint2*)pw          = w0;   // pp = 0 + (g4>>1)
          *(uint2*)(pw + 1024) = w1;   // pp = 2 + (g4>>1)
          *(uint2*)(pw + 2048) = w2;   // pp = 4 + (g4>>1)
          *(uint2*)(pw + 3072) = w3;   // pp = 6 + (g4>>1)
        }
        float ps = ((p0[0] + p0[1]) + (p0[2] + p0[3])) + ((p1[0] + p1[1]) + (p1[2] + p1[3]))
                 + ((p2[0] + p2[1]) + (p2[2] + p2[3])) + ((p3[0] + p3[1]) + (p3[2] + p3[3]));
        ps += __shfl_xor(ps, 16, 64);
        ps += __shfl_xor(ps, 32, 64);
        lr = lr * scl + ps;
        if (ph == NCH - 1 && g4 == 0) lfin[qs * 16 + c15] = lr;
      }
    } else {
      // ---- PV chunk ph-1 (issue bv global loads FIRST: older than K DMA)
      half8 bv[2][4];
      if (ph > 0) {
        const unsigned short* vt = vgb + (size_t)(ph - 1) * TILE;
#pragma unroll
        for (int t = 0; t < 2; ++t)
#pragma unroll
          for (int n = 0; n < 4; ++n)
            bv[t][n] = *(const half8*)(vt + (t * 4 + g4) * 4096 + (d0 + n * 16 + c15) * 8);
      }
      // ---- issue K(ph+1) DMA into Kl[pb]
      if (ph + 1 < NCH) {
        const unsigned short* ks_ = kg + (size_t)(ph + 1) * TILE;
#pragma unroll
        for (int ii = 0; ii < 8; ++ii)
          gload16(ks_ + ii * 4096, &Kl[pb][st * 8 + ii * 4096]);
      }
      if (ph > 0) {
        int4 f4 = *(const int4*)&rflag[pb][0];
        const int fl = f4.x | f4.y | f4.z | f4.w;
        if (fl) {
#pragma unroll
          for (int s = 0; s < 4; ++s) {
            f32x4 sv = *(const f32x4*)&sml[pb][s * 16 + rbase];
#pragma unroll
            for (int n = 0; n < 4; ++n)
#pragma unroll
              for (int j = 0; j < 4; ++j) acc[s * 4 + n][j] *= sv[j];
          }
        }
        // ---- MFMA with just-in-time pa loads (keeps live set ~112 VGPR:
        //      acc 64 + bv 32 + pa 16) -- r12 held all 8 pa live and spilled.
        __builtin_amdgcn_s_setprio(1);
#pragma unroll
        for (int t = 0; t < 2; ++t) {
          half8 pa0 = *(const half8*)&Pl[pb][(t * 4 + g4) * 512 + (0 * 16 + c15) * 8];
          half8 pa1 = *(const half8*)&Pl[pb][(t * 4 + g4) * 512 + (1 * 16 + c15) * 8];
          half8 pa2 = *(const half8*)&Pl[pb][(t * 4 + g4) * 512 + (2 * 16 + c15) * 8];
          half8 pa3 = *(const half8*)&Pl[pb][(t * 4 + g4) * 512 + (3 * 16 + c15) * 8];
#pragma unroll
          for (int n = 0; n < 4; ++n) {
            acc[0 * 4 + n] = __builtin_amdgcn_mfma_f32_16x16x32_f16(pa0, bv[t][n], acc[0 * 4 + n], 0, 0, 0);
            acc[1 * 4 + n] = __builtin_amdgcn_mfma_f32_16x16x32_f16(pa1, bv[t][n], acc[1 * 4 + n], 0, 0, 0);
            acc[2 * 4 + n] = __builtin_amdgcn_mfma_f32_16x16x32_f16(pa2, bv[t][n], acc[2 * 4 + n], 0, 0, 0);
            acc[3 * 4 + n] = __builtin_amdgcn_mfma_f32_16x16x32_f16(pa3, bv[t][n], acc[3 * 4 + n], 0, 0, 0);
          }
        }
        __builtin_amdgcn_s_setprio(0);
      }
    }

    // ---- single per-phase barrier: PV threads drain K DMA (+own loads);
    //      QK threads have no vmem outstanding.
    asm volatile("s_waitcnt vmcnt(0) lgkmcnt(0)" ::: "memory");
    __builtin_amdgcn_s_barrier();
    __builtin_amdgcn_sched_barrier(0);
  }

  // ---- epilogue (PV waves hold O): O /= l, store f32
  if (!isQK) {
#pragma unroll
    for (int s = 0; s < 4; ++s) {
      f32x4 lv = *(const f32x4*)&lfin[s * 16 + rbase];
      float inv[4];
#pragma unroll
      for (int j = 0; j < 4; ++j) inv[j] = 1.0f / lv[j];
      float* ob = Out + ((size_t)b * LQ + qt * QBLK + s * 16 + rbase) * DVD + d0 + c15;
#pragma unroll
      for (int n = 0; n < 4; ++n)
#pragma unroll
        for (int j = 0; j < 4; ++j)
          ob[(size_t)j * DVD + n * 16] = acc[s * 4 + n][j] * inv[j];
    }
  }
}

extern "C" void kernel_launch(void* const* d_in, const int* in_sizes, int n_in,
                              void* d_out, int out_size, void* d_ws, size_t ws_size,
                              hipStream_t stream) {
  const float* Qf = (const float*)d_in[0];
  const float* Kf = (const float*)d_in[1];
  const float* Vf = (const float*)d_in[2];
  float* Out = (float*)d_out;

  unsigned short* Kw = (unsigned short*)d_ws;
  unsigned short* Vw = Kw + (size_t)NB * NCH * TILE;   // 16.7 MB each

  prep_kv<<<NB * NCH * 2 * 2, 256, 0, stream>>>(Kf, Vf, Kw, Vw);
  attn_ws3<<<NB * (LQ / QBLK), 768, 0, stream>>>(Qf, Kw, Vw, Out);
}